// Round 13
// baseline (2009.602 us; speedup 1.0000x reference)
//
#include <hip/hip_runtime.h>
#include <cstdint>
#include <math.h>

// ConvDBN: 2-layer conv-RBM with Gumbel-max multinomial pooling.
// Numerics (R12-verified, absmax 0.0039): l1 exact f64 (h1 must stay exact --
// mixed l1 would leak ~3.5e-4 into l2 redo scores); l2 mixed: per-ic f32
// chunks folded into f64 acc ic-ascending, pool + top-2 gap exact f64,
// TAU=6e-3 (20x the ~3e-4 max statistical error over 7.1M draws), flagged
// outputs redone exactly from h1_f64. RNG: JAX threefry2x32 partitionable
// split, 32-bit draw = o0^o1, gumbel f32 rounding points exact.
// R13: l2 was LDS-INSTRUCTION-bound (108 b32/2 outputs). New l2: 2x2 quad per
// thread, hs f32 with ROW STRIDE 36 (thread base float idx 36R+6sb_w always
// even -> b64-mergeable; bank-tiled: b64 16-lane phases 12sb_h+3sb_w mod 16 =
// {0,3,6,9}+{0,12,8,4} = all 16; b32 32-lane phases 24sb_h+6sb_w = 16 distinct
// x2 broadcast lanes -> conflict-free EITHER way). Padding breaks DMA ->
// register-staged double-buffer, 1-chunk-ahead prefetch, one barrier/chunk.
// 128-thr blocks (8 oc x 16 sb), grid 24x64. Spill sentinel: WRITE_SIZE.

#define EPS_D 1e-8
#define INV_SIGMA2 (1.0 / (0.2 * 0.2))
#define TAU 6e-3
#define REDO_CAP 32768
#define H1_BYTES (5529600ull * 8ull)
#define H1F32_BYTES (5529600ull * 4ull)

__host__ __device__ __forceinline__ void threefry2x32(
    uint32_t k0, uint32_t k1, uint32_t x0, uint32_t x1,
    uint32_t* o0, uint32_t* o1) {
  const uint32_t ks0 = k0, ks1 = k1, ks2 = k0 ^ k1 ^ 0x1BD11BDAu;
  x0 += ks0; x1 += ks1;
#define TF_R(r) { x0 += x1; x1 = (x1 << (r)) | (x1 >> (32 - (r))); x1 ^= x0; }
  TF_R(13) TF_R(15) TF_R(26) TF_R(6)
  x0 += ks1; x1 += ks2 + 1u;
  TF_R(17) TF_R(29) TF_R(16) TF_R(24)
  x0 += ks2; x1 += ks0 + 2u;
  TF_R(13) TF_R(15) TF_R(26) TF_R(6)
  x0 += ks0; x1 += ks1 + 3u;
  TF_R(17) TF_R(29) TF_R(16) TF_R(24)
  x0 += ks1; x1 += ks2 + 4u;
  TF_R(13) TF_R(15) TF_R(26) TF_R(6)
  x0 += ks2; x1 += ks0 + 5u;
#undef TF_R
  *o0 = x0; *o1 = x1;
}

__device__ __forceinline__ double fast_log(double x) {
  long long ib = __double_as_longlong(x);
  int e = (int)((ib >> 52) & 0x7ff) - 1023;
  double r = __longlong_as_double((ib & 0xfffffffffffffLL) | 0x3ff0000000000000LL);
  if (r > 1.4142135623730951) { r *= 0.5; e += 1; }
  double s = (r - 1.0) / (r + 1.0);
  double s2 = s * s;
  double t = fma(s2, fma(s2, fma(s2, fma(s2, fma(s2, fma(s2,
      1.0/15.0, 1.0/13.0), 1.0/11.0), 1.0/9.0), 1.0/7.0), 1.0/5.0), 1.0/3.0);
  double lr = fma(2.0 * s * s2, t, 2.0 * s);
  return fma((double)e, 0.6931471805599453, lr);
}

__device__ __forceinline__ double fast_exp(double x) {
  double nd = rint(x * 1.4426950408889634);
  double f = fma(nd, -0.6931471803691238, x);
  f = fma(nd, -1.9082149292705877e-10, f);
  double p = 2.505210838544172e-8;
  p = fma(p, f, 2.755731922398589e-7);
  p = fma(p, f, 2.7557319223985893e-6);
  p = fma(p, f, 2.48015873015873e-5);
  p = fma(p, f, 1.984126984126984e-4);
  p = fma(p, f, 1.3888888888888889e-3);
  p = fma(p, f, 8.333333333333333e-3);
  p = fma(p, f, 4.1666666666666664e-2);
  p = fma(p, f, 0.16666666666666666);
  p = fma(p, f, 0.5);
  p = fma(p, f, 1.0);
  p = fma(p, f, 1.0);
  return ldexp(p, (int)nd);
}

__device__ __forceinline__ double gumbel_pool9(const double (&acc)[9],
                                               double bb, uint64_t base,
                                               uint32_t kp0, uint32_t kp1) {
  double bestv = -1e308, bA = 1.0, bQ = 0.0;
#pragma unroll
  for (int k = 0; k < 9; ++k) {
    double pre = (acc[k] + bb) * INV_SIGMA2;
    double q = fast_exp(-fabs(pre));
    double A = pre >= 0.0 ? 1.0 : q;          // p = A/(1+q)
    double opq = 1.0 + q;
    double L = fast_log(fma(EPS_D, opq, A)) - fast_log(opq);
    uint32_t o0, o1;
    uint64_t idx = base + (uint64_t)k;
    threefry2x32(kp0, kp1, (uint32_t)(idx >> 32), (uint32_t)idx, &o0, &o1);
    uint32_t bits = o0 ^ o1;
    float u = __uint_as_float((bits >> 9) | 0x3f800000u) - 1.0f;
    if (u == 0.0f) u = 1.17549435e-38f;
    float lg1 = (float)fast_log((double)u);
    double lg2 = fast_log(-(double)lg1);
    float gf = -(float)lg2;
    double v = L + (double)gf;
    if (v > bestv) { bestv = v; bA = A; bQ = q; }   // first-occurrence argmax
  }
  return bA / (1.0 + bQ);
}

__device__ __forceinline__ double gumbel_pool9_gap(const double (&acc)[9],
                                                   double bb, uint64_t base,
                                                   uint32_t kp0, uint32_t kp1,
                                                   double* gap) {
  double bestv = -1e308, second = -1e308, bA = 1.0, bQ = 0.0;
#pragma unroll
  for (int k = 0; k < 9; ++k) {
    double pre = (acc[k] + bb) * INV_SIGMA2;
    double q = fast_exp(-fabs(pre));
    double A = pre >= 0.0 ? 1.0 : q;
    double opq = 1.0 + q;
    double L = fast_log(fma(EPS_D, opq, A)) - fast_log(opq);
    uint32_t o0, o1;
    uint64_t idx = base + (uint64_t)k;
    threefry2x32(kp0, kp1, (uint32_t)(idx >> 32), (uint32_t)idx, &o0, &o1);
    uint32_t bits = o0 ^ o1;
    float u = __uint_as_float((bits >> 9) | 0x3f800000u) - 1.0f;
    if (u == 0.0f) u = 1.17549435e-38f;
    float lg1 = (float)fast_log((double)u);
    double lg2 = fast_log(-(double)lg1);
    float gf = -(float)lg2;
    double v = L + (double)gf;
    if (v > bestv) { second = bestv; bestv = v; bA = A; bQ = q; }
    else if (v > second) second = v;
  }
  *gap = bestv - second;
  return bA / (1.0 + bQ);
}

// ---- f64 vertical output pair (l1 + fallback l2; R8-verified) ----
template <int LDSTRIDE, typename T>
__device__ __forceinline__ void conv_pair(const T* __restrict__ xb,
                                          const double (&w)[49],
                                          double (&a0)[9], double (&a1)[9]) {
#pragma unroll
  for (int pr = 0; pr < 12; ++pr) {
    double xr[9];
#pragma unroll
    for (int c = 0; c < 9; ++c) xr[c] = (double)xb[pr * LDSTRIDE + c];
#pragma unroll
    for (int ki = 0; ki < 3; ++ki) {
      const int u0 = pr - ki;
      if (u0 >= 0 && u0 <= 6) {
#pragma unroll
        for (int kj = 0; kj < 3; ++kj)
#pragma unroll
          for (int v = 0; v < 7; ++v)
            a0[ki * 3 + kj] = fma(xr[kj + v], w[u0 * 7 + v], a0[ki * 3 + kj]);
      }
      const int u1 = pr - 3 - ki;
      if (u1 >= 0 && u1 <= 6) {
#pragma unroll
        for (int kj = 0; kj < 3; ++kj)
#pragma unroll
          for (int v = 0; v < 7; ++v)
            a1[ki * 3 + kj] = fma(xr[kj + v], w[u1 * 7 + v], a1[ki * 3 + kj]);
      }
    }
  }
}

// ---- l2 quad: one patch row PR (literal), 2x2 outputs, f32 chunk accs.
// xr[12] spans cols 6sb_w..+11; right outputs (c2=1) offset +3 floats.
// Order per acc: PR asc -> kh asc, v asc == reference order within chunk.
template <int PR>
__device__ __forceinline__ void quad_step36(const float* __restrict__ xb,
                                            const float (&w)[49],
                                            float (&c00)[9], float (&c01)[9],
                                            float (&c10)[9], float (&c11)[9]) {
  float xr[12];
#pragma unroll
  for (int c = 0; c < 12; ++c) xr[c] = xb[PR * 36 + c];
#pragma unroll
  for (int ki = 0; ki < 3; ++ki) {
    const int u0 = PR - ki;
    if (u0 >= 0 && u0 <= 6) {
#pragma unroll
      for (int kj = 0; kj < 3; ++kj)
#pragma unroll
        for (int v = 0; v < 7; ++v) {
          c00[ki * 3 + kj] = fmaf(xr[kj + v],     w[u0 * 7 + v], c00[ki * 3 + kj]);
          c01[ki * 3 + kj] = fmaf(xr[3 + kj + v], w[u0 * 7 + v], c01[ki * 3 + kj]);
        }
    }
    const int u1 = PR - 3 - ki;
    if (u1 >= 0 && u1 <= 6) {
#pragma unroll
      for (int kj = 0; kj < 3; ++kj)
#pragma unroll
        for (int v = 0; v < 7; ++v) {
          c10[ki * 3 + kj] = fmaf(xr[kj + v],     w[u1 * 7 + v], c10[ki * 3 + kj]);
          c11[ki * 3 + kj] = fmaf(xr[3 + kj + v], w[u1 * 7 + v], c11[ki * 3 + kj]);
        }
    }
  }
}

// ---------------- Layer 1 (f64, R8-verified; optional f32 shadow) ----------
__global__ __launch_bounds__(256, 3) void l1_kernel(
    const float* __restrict__ x, const float* __restrict__ W1,
    const float* __restrict__ b1, double* __restrict__ h1,
    float* __restrict__ h1f32, int write_f32,
    uint32_t kp0, uint32_t kp1) {
  const int oc   = blockIdx.x;   // 96
  const int b    = blockIdx.y;   // 64
  const int half = blockIdx.z;   // 2
  const int t = threadIdx.x;
  const int wave = t >> 6;

  __shared__ float xs[54 * 96];   // 20,736 B

  const int p0 = 14 * half;
  const bool active = t < 240;
  const int q = t / 30, bw = t - q * 30;
  const float* xb = xs + (6 * q) * 96 + 3 * bw;

  double a0[9] = {}, a1[9] = {};
  double w[49];

#pragma unroll 1
  for (int ic = 0; ic < 3; ++ic) {
    __syncthreads();
    {
      const char* gsrc = (const char*)(x + ((size_t)b * 3 + ic) * 9216 + (3 * p0) * 96);
#pragma unroll
      for (int p = 0; p < 6; ++p) {
        int elt = p * 256 + t;
        if (elt < 1296) {
          __builtin_amdgcn_global_load_lds(
              (const __attribute__((address_space(1))) void*)(gsrc + (size_t)elt * 16),
              (__attribute__((address_space(3))) void*)((char*)xs +
                                                        (size_t)(p * 256 + wave * 64) * 16),
              16, 0, 0);
        }
      }
    }
    __syncthreads();
    {
      const float* __restrict__ wsrc = W1 + (oc * 3 + ic) * 49;
#pragma unroll
      for (int j = 0; j < 49; ++j) w[j] = (double)wsrc[j];
    }
    if (active) conv_pair<96, float>(xb, w, a0, a1);
  }

  if (active) {
    const double bb = (double)b1[oc];
    const int bh0 = p0 + 2 * q;
#pragma unroll
    for (int j = 0; j < 2; ++j) {
      const int pos = (bh0 + j) * 30 + bw;
      const uint64_t base = ((uint64_t)((b * 96 + oc) * 900 + pos)) * 9ull;
      double pooled = gumbel_pool9(j ? a1 : a0, bb, base, kp0, kp1);
      const size_t oidx = (size_t)(b * 96 + oc) * 900 + pos;
      h1[oidx] = pooled;
      if (write_f32) h1f32[oidx] = (float)pooled;  // == cvt-on-read, bitwise
    }
  }
}

__global__ void init_kernel(unsigned int* cnt) {
  if (threadIdx.x == 0 && blockIdx.x == 0) *cnt = 0u;
}

// ---------------- Layer 2 main: mixed 2x2 quad, stride-36 f32 LDS ----------
// Block = 128 thr = 8 oc x 16 sb; thread computes a 2x2 pooled quad.
// T = float (h1f32) or double (h1 f64; cvt at LDS write, bit-identical input).
template <typename T>
__global__ __launch_bounds__(128, 2) void l2_kernel_quad(
    const T* __restrict__ hsrc, const float* __restrict__ W2,
    const float* __restrict__ b2, float* __restrict__ out,
    unsigned int* __restrict__ cnt, unsigned int* __restrict__ list,
    uint32_t kp0, uint32_t kp1) {
  const int octile = blockIdx.x;  // 24
  const int b      = blockIdx.y;  // 64
  const int t = threadIdx.x;      // 128
  const int oc_local = t >> 4;    // 0..7, quarter-wave uniform
  const int sb = t & 15;
  const int sb_h = sb >> 2, sb_w = sb & 3;
  const int oc = octile * 8 + oc_local;

  __shared__ float hs[2][30 * 36];   // 8,640 B (stride 36: bank-tiled)
  __shared__ float wsf[2][392];      // 3,136 B (8 oc x 49)

  const T* __restrict__ hb = hsrc + (size_t)b * 86400;
  const float* __restrict__ wg = W2 + (size_t)octile * 8 * 4704;

  // Per-thread staging slots (fixed across chunks): hs 900 elems, wsf 392.
  int hj[8], hladdr[8];
  bool hv[8];
#pragma unroll
  for (int p = 0; p < 8; ++p) {
    int j = p * 128 + t;
    hv[p] = j < 900;
    hj[p] = hv[p] ? j : 0;
    int r = hj[p] / 30, cc = hj[p] - r * 30;
    hladdr[p] = r * 36 + cc;
  }
  int wj[4];
  size_t wbase[4];
  bool wv[4];
#pragma unroll
  for (int p = 0; p < 4; ++p) {
    int j = p * 128 + t;
    wv[p] = j < 392;
    wj[p] = wv[p] ? j : 0;
    int oi = wj[p] / 49, rem = wj[p] - oi * 49;
    wbase[p] = (size_t)oi * 4704 + rem;
  }

  float hr[8], wr[4];
  // chunk 0 into regs, then LDS buf0; chunk 1 into regs.
#pragma unroll
  for (int p = 0; p < 8; ++p) if (hv[p]) hr[p] = (float)hb[hj[p]];
#pragma unroll
  for (int p = 0; p < 4; ++p) if (wv[p]) wr[p] = wg[wbase[p]];
#pragma unroll
  for (int p = 0; p < 8; ++p) if (hv[p]) hs[0][hladdr[p]] = hr[p];
#pragma unroll
  for (int p = 0; p < 4; ++p) if (wv[p]) wsf[0][wj[p]] = wr[p];
#pragma unroll
  for (int p = 0; p < 8; ++p) if (hv[p]) hr[p] = (float)hb[900 + hj[p]];
#pragma unroll
  for (int p = 0; p < 4; ++p) if (wv[p]) wr[p] = wg[wbase[p] + 49];

  double a00[9] = {}, a01[9] = {}, a10[9] = {}, a11[9] = {};
  float w[49];
  const float* xbase0 = &hs[0][(6 * sb_h) * 36 + 6 * sb_w];
  const float* xbase1 = &hs[1][(6 * sb_h) * 36 + 6 * sb_w];

#pragma unroll 1
  for (int c = 0; c < 96; ++c) {
    __syncthreads();   // buf c&1 writes drained; readers of buf (c+1)&1 done
    if (c + 1 < 96) {
      const int nb = (c + 1) & 1;
#pragma unroll
      for (int p = 0; p < 8; ++p) if (hv[p]) hs[nb][hladdr[p]] = hr[p];
#pragma unroll
      for (int p = 0; p < 4; ++p) if (wv[p]) wsf[nb][wj[p]] = wr[p];
      if (c + 2 < 96) {
#pragma unroll
        for (int p = 0; p < 8; ++p)
          if (hv[p]) hr[p] = (float)hb[(size_t)(c + 2) * 900 + hj[p]];
#pragma unroll
        for (int p = 0; p < 4; ++p)
          if (wv[p]) wr[p] = wg[wbase[p] + (size_t)(c + 2) * 49];
      }
    }
    {
      const float* __restrict__ wsrc = &wsf[c & 1][oc_local * 49];
#pragma unroll
      for (int j = 0; j < 49; ++j) w[j] = wsrc[j];   // quarter-uniform bcast
      const float* xb = (c & 1) ? xbase1 : xbase0;
      float c00[9] = {}, c01[9] = {}, c10[9] = {}, c11[9] = {};
      quad_step36<0>(xb, w, c00, c01, c10, c11);
      quad_step36<1>(xb, w, c00, c01, c10, c11);
      quad_step36<2>(xb, w, c00, c01, c10, c11);
      quad_step36<3>(xb, w, c00, c01, c10, c11);
      quad_step36<4>(xb, w, c00, c01, c10, c11);
      quad_step36<5>(xb, w, c00, c01, c10, c11);
      quad_step36<6>(xb, w, c00, c01, c10, c11);
      quad_step36<7>(xb, w, c00, c01, c10, c11);
      quad_step36<8>(xb, w, c00, c01, c10, c11);
      quad_step36<9>(xb, w, c00, c01, c10, c11);
      quad_step36<10>(xb, w, c00, c01, c10, c11);
      quad_step36<11>(xb, w, c00, c01, c10, c11);
#pragma unroll
      for (int k = 0; k < 9; ++k) {
        a00[k] += (double)c00[k]; a01[k] += (double)c01[k];
        a10[k] += (double)c10[k]; a11[k] += (double)c11[k];
      }
    }
  }

  const double bb = (double)b2[oc];
#pragma unroll
  for (int r = 0; r < 2; ++r)
#pragma unroll
    for (int c2 = 0; c2 < 2; ++c2) {
      const int bh = 2 * sb_h + r, bwp = 2 * sb_w + c2;
      const unsigned int oid = (unsigned int)((b * 192 + oc) * 64 + bh * 8 + bwp);
      const uint64_t base = (uint64_t)oid * 9ull;
      double gap;
      const double (&ar)[9] = r ? (c2 ? a11 : a10) : (c2 ? a01 : a00);
      double pooled = gumbel_pool9_gap(ar, bb, base, kp0, kp1, &gap);
      out[oid] = (float)pooled;
      if (gap < TAU) {
        unsigned int idx = atomicAdd(cnt, 1u);
        if (idx < REDO_CAP) list[idx] = oid;
      }
    }
}

// ---------------- Layer 2 fallback (pure f64, R8/R12-verified) -------------
__global__ __launch_bounds__(256, 3) void l2_kernel_f64(
    const double* __restrict__ h1, const float* __restrict__ W2,
    const float* __restrict__ b2, float* __restrict__ out,
    uint32_t kp0, uint32_t kp1) {
  const int octile = blockIdx.x;
  const int b      = blockIdx.y;
  const int t = threadIdx.x;
  const int wave = t >> 6;
  const int oc_local = t >> 5;
  const int li = t & 31;
  const int bw = li & 7;
  const int ph = 2 * ((li >> 3) & 1) + (li >> 4);
  const int bh0 = 2 * ph;
  const int oc = octile * 8 + oc_local;

  __shared__ double hs[2][900];
  __shared__ double wsd[2][392];

  const double* __restrict__ hb = h1 + (size_t)b * 86400;
  const float* __restrict__ wg = W2 + (size_t)octile * 8 * 4704;

  double a0[9] = {}, a1[9] = {};
  double w[49];

  auto stage = [&](int c, int buf) {
    const char* gsrc = (const char*)(hb + (size_t)c * 900);
#pragma unroll
    for (int p = 0; p < 2; ++p) {
      int elt = p * 256 + t;
      if (elt < 450) {
        __builtin_amdgcn_global_load_lds(
            (const __attribute__((address_space(1))) void*)(gsrc + (size_t)elt * 16),
            (__attribute__((address_space(3))) void*)((char*)&hs[buf][0] +
                                                      (size_t)(p * 256 + wave * 64) * 16),
            16, 0, 0);
      }
    }
#pragma unroll
    for (int p = 0; p < 2; ++p) {   // TWO passes (392 > 256)
      int j = p * 256 + t;
      if (j < 392) {
        int oi = j / 49, rem = j - oi * 49;
        wsd[buf][j] = (double)wg[(size_t)oi * 4704 + c * 49 + rem];
      }
    }
  };

  stage(0, 0);
#pragma unroll 1
  for (int c = 0; c < 96; ++c) {
    __syncthreads();
    if (c + 1 < 96) stage(c + 1, (c + 1) & 1);
    {
      const double* __restrict__ wsrc = &wsd[c & 1][oc_local * 49];
#pragma unroll
      for (int j = 0; j < 49; ++j) w[j] = wsrc[j];
      const double* xb = &hs[c & 1][(6 * ph) * 30 + 3 * bw];
      conv_pair<30, double>(xb, w, a0, a1);
    }
  }

  const double bb = (double)b2[oc];
#pragma unroll
  for (int j = 0; j < 2; ++j) {
    const int bh = bh0 + j;
    const uint64_t base = ((uint64_t)(((b * 192 + oc) * 8 + bh) * 8 + bw)) * 9ull;
    double pooled = gumbel_pool9(j ? a1 : a0, bb, base, kp0, kp1);
    out[(size_t)(b * 192 + oc) * 64 + bh * 8 + bw] = (float)pooled;
  }
}

// ---------------- Layer 2 tie-redo (exact f64 from h1_f64) ----------------
__global__ __launch_bounds__(64) void l2_redo_kernel(
    const double* __restrict__ h1, const float* __restrict__ W2,
    const float* __restrict__ b2, float* __restrict__ out,
    const unsigned int* __restrict__ cnt, const unsigned int* __restrict__ list,
    uint32_t kp0, uint32_t kp1) {
  unsigned int n = *cnt;
  if (n > REDO_CAP) n = REDO_CAP;
  if (blockIdx.x >= n) return;
  const unsigned int oid = list[blockIdx.x];
  const int sp = oid & 63, bh = sp >> 3, bw = sp & 7;
  const int rest = oid >> 6, oc = rest % 192, b = rest / 192;
  const int lane = threadIdx.x;

  double acc[9] = {};
  for (int ic = lane; ic < 96; ic += 64) {
    const double* __restrict__ xp =
        h1 + ((size_t)(b * 96 + ic) * 30 + 3 * bh) * 30 + 3 * bw;
    const float* __restrict__ wp = W2 + ((size_t)oc * 96 + ic) * 49;
    double w[49];
#pragma unroll
    for (int j = 0; j < 49; ++j) w[j] = (double)wp[j];
#pragma unroll
    for (int pr = 0; pr < 9; ++pr) {
      double xr[9];
#pragma unroll
      for (int c = 0; c < 9; ++c) xr[c] = xp[pr * 30 + c];
#pragma unroll
      for (int kh = 0; kh < 3; ++kh) {
        const int u = pr - kh;
        if (u >= 0 && u <= 6) {
#pragma unroll
          for (int kw = 0; kw < 3; ++kw)
#pragma unroll
            for (int v = 0; v < 7; ++v)
              acc[kh * 3 + kw] = fma(xr[kw + v], w[u * 7 + v], acc[kh * 3 + kw]);
        }
      }
    }
  }
#pragma unroll
  for (int off = 32; off; off >>= 1)
#pragma unroll
    for (int k = 0; k < 9; ++k) acc[k] += __shfl_down(acc[k], off);

  if (lane == 0) {
    const uint64_t base = (uint64_t)oid * 9ull;
    double pooled = gumbel_pool9(acc, (double)b2[oc], base, kp0, kp1);
    out[oid] = (float)pooled;
  }
}

extern "C" void kernel_launch(void* const* d_in, const int* in_sizes, int n_in,
                              void* d_out, int out_size, void* d_ws,
                              size_t ws_size, hipStream_t stream) {
  const float* x  = (const float*)d_in[0];   // [64,3,96,96]
  const float* W1 = (const float*)d_in[1];   // [96,3,7,7]
  const float* b1 = (const float*)d_in[2];   // [96]
  const float* W2 = (const float*)d_in[3];   // [192,96,7,7]
  const float* b2 = (const float*)d_in[4];   // [192]
  float* out = (float*)d_out;                // [64,192,8,8]
  double* h1   = (double*)d_ws;              // 44.24 MB f64
  float* h1f32 = (float*)((char*)d_ws + H1_BYTES);  // 22.12 MB f32 (full tier)

  uint32_t kp1a, kp1b, kp2a, kp2b;
  threefry2x32(0u, 42u, 0u, 0u, &kp1a, &kp1b);
  threefry2x32(0u, 42u, 0u, 1u, &kp2a, &kp2b);

  const size_t need_full = H1_BYTES + H1F32_BYTES + 16 + (size_t)REDO_CAP * 4;
  const size_t need_mid  = H1_BYTES + 16 + (size_t)REDO_CAP * 4;

  if (ws_size >= need_full) {          // launch-constant branches: graph-safe
    unsigned int* cnt  = (unsigned int*)((char*)d_ws + H1_BYTES + H1F32_BYTES);
    unsigned int* list = cnt + 4;
    l1_kernel<<<dim3(96, 64, 2), 256, 0, stream>>>(x, W1, b1, h1, h1f32, 1,
                                                   kp1a, kp1b);
    init_kernel<<<1, 64, 0, stream>>>(cnt);
    l2_kernel_quad<float><<<dim3(24, 64), 128, 0, stream>>>(
        h1f32, W2, b2, out, cnt, list, kp2a, kp2b);
    l2_redo_kernel<<<REDO_CAP, 64, 0, stream>>>(h1, W2, b2, out, cnt, list,
                                                kp2a, kp2b);
  } else if (ws_size >= need_mid) {
    unsigned int* cnt  = (unsigned int*)((char*)d_ws + H1_BYTES);
    unsigned int* list = cnt + 4;
    l1_kernel<<<dim3(96, 64, 2), 256, 0, stream>>>(x, W1, b1, h1, h1f32, 0,
                                                   kp1a, kp1b);
    init_kernel<<<1, 64, 0, stream>>>(cnt);
    l2_kernel_quad<double><<<dim3(24, 64), 128, 0, stream>>>(
        h1, W2, b2, out, cnt, list, kp2a, kp2b);
    l2_redo_kernel<<<REDO_CAP, 64, 0, stream>>>(h1, W2, b2, out, cnt, list,
                                                kp2a, kp2b);
  } else {
    l1_kernel<<<dim3(96, 64, 2), 256, 0, stream>>>(x, W1, b1, h1, h1f32, 0,
                                                   kp1a, kp1b);
    l2_kernel_f64<<<dim3(24, 64), 256, 0, stream>>>(h1, W2, b2, out,
                                                    kp2a, kp2b);
  }
}

// Round 14
// 1734.916 us; speedup vs baseline: 1.1583x; 1.1583x over previous
//
#include <hip/hip_runtime.h>
#include <cstdint>
#include <math.h>

// ConvDBN: 2-layer conv-RBM with Gumbel-max multinomial pooling.
// Numerics (R12-verified, absmax 0.0039): l1 exact f64 (h1 must stay exact);
// l2 mixed: per-ic f32 chunks folded into f64 acc ic-ascending, pool + top-2
// gap exact f64, TAU=6e-3, flagged outputs redone exactly from h1_f64.
// RNG: JAX threefry2x32 partitionable split, 32-bit draw = o0^o1.
// R14: R13's 2x2 quad blew up VALU via AGPR moves (72 f64 accs > VGPR budget).
// Keep R12's register-clean shape (18 f64 + 18 f32 accs, 84 VGPR) but halve
// LDS instructions: 1x2 HORIZONTAL pair, hs row stride 38 (row base
// 114bh+6(sp&3) floats is even -> explicit float2 = ds_read_b64: 54 hs + 25 w
// reads/thread-chunk vs R12's 157). Banks: b64 16-lane phases 9bh+3c mod 16
// max 2-way (free, m136); w stride 52 -> float2, quarter-uniform broadcast.
// Padding breaks DMA -> register-staged double-buffer (coverage: 4x256=1024
// >= 900, 2x256=512 >= 392 -- audited, the R10/R11 bug class). init folded
// into l1. Spill sentinel: WRITE_SIZE (~3 KB expected).

#define EPS_D 1e-8
#define INV_SIGMA2 (1.0 / (0.2 * 0.2))
#define TAU 6e-3
#define REDO_CAP 32768
#define H1_BYTES (5529600ull * 8ull)
#define H1F32_BYTES (5529600ull * 4ull)

__host__ __device__ __forceinline__ void threefry2x32(
    uint32_t k0, uint32_t k1, uint32_t x0, uint32_t x1,
    uint32_t* o0, uint32_t* o1) {
  const uint32_t ks0 = k0, ks1 = k1, ks2 = k0 ^ k1 ^ 0x1BD11BDAu;
  x0 += ks0; x1 += ks1;
#define TF_R(r) { x0 += x1; x1 = (x1 << (r)) | (x1 >> (32 - (r))); x1 ^= x0; }
  TF_R(13) TF_R(15) TF_R(26) TF_R(6)
  x0 += ks1; x1 += ks2 + 1u;
  TF_R(17) TF_R(29) TF_R(16) TF_R(24)
  x0 += ks2; x1 += ks0 + 2u;
  TF_R(13) TF_R(15) TF_R(26) TF_R(6)
  x0 += ks0; x1 += ks1 + 3u;
  TF_R(17) TF_R(29) TF_R(16) TF_R(24)
  x0 += ks1; x1 += ks2 + 4u;
  TF_R(13) TF_R(15) TF_R(26) TF_R(6)
  x0 += ks2; x1 += ks0 + 5u;
#undef TF_R
  *o0 = x0; *o1 = x1;
}

__device__ __forceinline__ double fast_log(double x) {
  long long ib = __double_as_longlong(x);
  int e = (int)((ib >> 52) & 0x7ff) - 1023;
  double r = __longlong_as_double((ib & 0xfffffffffffffLL) | 0x3ff0000000000000LL);
  if (r > 1.4142135623730951) { r *= 0.5; e += 1; }
  double s = (r - 1.0) / (r + 1.0);
  double s2 = s * s;
  double t = fma(s2, fma(s2, fma(s2, fma(s2, fma(s2, fma(s2,
      1.0/15.0, 1.0/13.0), 1.0/11.0), 1.0/9.0), 1.0/7.0), 1.0/5.0), 1.0/3.0);
  double lr = fma(2.0 * s * s2, t, 2.0 * s);
  return fma((double)e, 0.6931471805599453, lr);
}

__device__ __forceinline__ double fast_exp(double x) {
  double nd = rint(x * 1.4426950408889634);
  double f = fma(nd, -0.6931471803691238, x);
  f = fma(nd, -1.9082149292705877e-10, f);
  double p = 2.505210838544172e-8;
  p = fma(p, f, 2.755731922398589e-7);
  p = fma(p, f, 2.7557319223985893e-6);
  p = fma(p, f, 2.48015873015873e-5);
  p = fma(p, f, 1.984126984126984e-4);
  p = fma(p, f, 1.3888888888888889e-3);
  p = fma(p, f, 8.333333333333333e-3);
  p = fma(p, f, 4.1666666666666664e-2);
  p = fma(p, f, 0.16666666666666666);
  p = fma(p, f, 0.5);
  p = fma(p, f, 1.0);
  p = fma(p, f, 1.0);
  return ldexp(p, (int)nd);
}

__device__ __forceinline__ double gumbel_pool9(const double (&acc)[9],
                                               double bb, uint64_t base,
                                               uint32_t kp0, uint32_t kp1) {
  double bestv = -1e308, bA = 1.0, bQ = 0.0;
#pragma unroll
  for (int k = 0; k < 9; ++k) {
    double pre = (acc[k] + bb) * INV_SIGMA2;
    double q = fast_exp(-fabs(pre));
    double A = pre >= 0.0 ? 1.0 : q;          // p = A/(1+q)
    double opq = 1.0 + q;
    double L = fast_log(fma(EPS_D, opq, A)) - fast_log(opq);
    uint32_t o0, o1;
    uint64_t idx = base + (uint64_t)k;
    threefry2x32(kp0, kp1, (uint32_t)(idx >> 32), (uint32_t)idx, &o0, &o1);
    uint32_t bits = o0 ^ o1;
    float u = __uint_as_float((bits >> 9) | 0x3f800000u) - 1.0f;
    if (u == 0.0f) u = 1.17549435e-38f;
    float lg1 = (float)fast_log((double)u);
    double lg2 = fast_log(-(double)lg1);
    float gf = -(float)lg2;
    double v = L + (double)gf;
    if (v > bestv) { bestv = v; bA = A; bQ = q; }   // first-occurrence argmax
  }
  return bA / (1.0 + bQ);
}

__device__ __forceinline__ double gumbel_pool9_gap(const double (&acc)[9],
                                                   double bb, uint64_t base,
                                                   uint32_t kp0, uint32_t kp1,
                                                   double* gap) {
  double bestv = -1e308, second = -1e308, bA = 1.0, bQ = 0.0;
#pragma unroll
  for (int k = 0; k < 9; ++k) {
    double pre = (acc[k] + bb) * INV_SIGMA2;
    double q = fast_exp(-fabs(pre));
    double A = pre >= 0.0 ? 1.0 : q;
    double opq = 1.0 + q;
    double L = fast_log(fma(EPS_D, opq, A)) - fast_log(opq);
    uint32_t o0, o1;
    uint64_t idx = base + (uint64_t)k;
    threefry2x32(kp0, kp1, (uint32_t)(idx >> 32), (uint32_t)idx, &o0, &o1);
    uint32_t bits = o0 ^ o1;
    float u = __uint_as_float((bits >> 9) | 0x3f800000u) - 1.0f;
    if (u == 0.0f) u = 1.17549435e-38f;
    float lg1 = (float)fast_log((double)u);
    double lg2 = fast_log(-(double)lg1);
    float gf = -(float)lg2;
    double v = L + (double)gf;
    if (v > bestv) { second = bestv; bestv = v; bA = A; bQ = q; }
    else if (v > second) second = v;
  }
  *gap = bestv - second;
  return bA / (1.0 + bQ);
}

// ---- f64 vertical output pair (l1 + fallback l2; R8-verified) ----
template <int LDSTRIDE, typename T>
__device__ __forceinline__ void conv_pair(const T* __restrict__ xb,
                                          const double (&w)[49],
                                          double (&a0)[9], double (&a1)[9]) {
#pragma unroll
  for (int pr = 0; pr < 12; ++pr) {
    double xr[9];
#pragma unroll
    for (int c = 0; c < 9; ++c) xr[c] = (double)xb[pr * LDSTRIDE + c];
#pragma unroll
    for (int ki = 0; ki < 3; ++ki) {
      const int u0 = pr - ki;
      if (u0 >= 0 && u0 <= 6) {
#pragma unroll
        for (int kj = 0; kj < 3; ++kj)
#pragma unroll
          for (int v = 0; v < 7; ++v)
            a0[ki * 3 + kj] = fma(xr[kj + v], w[u0 * 7 + v], a0[ki * 3 + kj]);
      }
      const int u1 = pr - 3 - ki;
      if (u1 >= 0 && u1 <= 6) {
#pragma unroll
        for (int kj = 0; kj < 3; ++kj)
#pragma unroll
          for (int v = 0; v < 7; ++v)
            a1[ki * 3 + kj] = fma(xr[kj + v], w[u1 * 7 + v], a1[ki * 3 + kj]);
      }
    }
  }
}

// ---- l2 horizontal-pair step: one patch row PR (0..8), outputs (bh, bwp0)
// and (bh, bwp0+1). 12 cols via 6 explicit float2 (ds_read_b64). Order per
// acc: PR asc -> u asc for fixed kh, v asc == reference order within chunk.
template <int PR>
__device__ __forceinline__ void hp_step38(const float* __restrict__ xb,
                                          const float (&w)[49],
                                          float (&c0)[9], float (&c1)[9]) {
  float xr[12];
  const float2* __restrict__ row = (const float2*)(xb + PR * 38);  // even base
#pragma unroll
  for (int k = 0; k < 6; ++k) { float2 v2 = row[k]; xr[2 * k] = v2.x; xr[2 * k + 1] = v2.y; }
#pragma unroll
  for (int kh = 0; kh < 3; ++kh) {
    const int u = PR - kh;
    if (u >= 0 && u <= 6) {
#pragma unroll
      for (int kw = 0; kw < 3; ++kw)
#pragma unroll
        for (int v = 0; v < 7; ++v) {
          c0[kh * 3 + kw] = fmaf(xr[kw + v],     w[u * 7 + v], c0[kh * 3 + kw]);
          c1[kh * 3 + kw] = fmaf(xr[3 + kw + v], w[u * 7 + v], c1[kh * 3 + kw]);
        }
    }
  }
}

// ---------------- Layer 1 (f64, R8-verified; f32 shadow + init fold) -------
__global__ __launch_bounds__(256, 3) void l1_kernel(
    const float* __restrict__ x, const float* __restrict__ W1,
    const float* __restrict__ b1, double* __restrict__ h1,
    float* __restrict__ h1f32, int write_f32, unsigned int* __restrict__ cnt,
    uint32_t kp0, uint32_t kp1) {
  const int oc   = blockIdx.x;   // 96
  const int b    = blockIdx.y;   // 64
  const int half = blockIdx.z;   // 2
  const int t = threadIdx.x;
  const int wave = t >> 6;

  if (cnt && oc == 0 && b == 0 && half == 0 && t == 0) *cnt = 0u;

  __shared__ float xs[54 * 96];   // 20,736 B

  const int p0 = 14 * half;
  const bool active = t < 240;
  const int q = t / 30, bw = t - q * 30;
  const float* xb = xs + (6 * q) * 96 + 3 * bw;

  double a0[9] = {}, a1[9] = {};
  double w[49];

#pragma unroll 1
  for (int ic = 0; ic < 3; ++ic) {
    __syncthreads();
    {
      const char* gsrc = (const char*)(x + ((size_t)b * 3 + ic) * 9216 + (3 * p0) * 96);
#pragma unroll
      for (int p = 0; p < 6; ++p) {
        int elt = p * 256 + t;
        if (elt < 1296) {
          __builtin_amdgcn_global_load_lds(
              (const __attribute__((address_space(1))) void*)(gsrc + (size_t)elt * 16),
              (__attribute__((address_space(3))) void*)((char*)xs +
                                                        (size_t)(p * 256 + wave * 64) * 16),
              16, 0, 0);
        }
      }
    }
    __syncthreads();
    {
      const float* __restrict__ wsrc = W1 + (oc * 3 + ic) * 49;
#pragma unroll
      for (int j = 0; j < 49; ++j) w[j] = (double)wsrc[j];
    }
    if (active) conv_pair<96, float>(xb, w, a0, a1);
  }

  if (active) {
    const double bb = (double)b1[oc];
    const int bh0 = p0 + 2 * q;
#pragma unroll
    for (int j = 0; j < 2; ++j) {
      const int pos = (bh0 + j) * 30 + bw;
      const uint64_t base = ((uint64_t)((b * 96 + oc) * 900 + pos)) * 9ull;
      double pooled = gumbel_pool9(j ? a1 : a0, bb, base, kp0, kp1);
      const size_t oidx = (size_t)(b * 96 + oc) * 900 + pos;
      h1[oidx] = pooled;
      if (write_f32) h1f32[oidx] = (float)pooled;  // == cvt-on-read, bitwise
    }
  }
}

// ---------------- Layer 2 main: mixed horizontal-pair, stride-38 f32 LDS ----
// 256 thr = 8 oc (half-wave uniform) x 32 sp (8 bh x 4 col-pairs); thread
// computes outputs (bh, 2*(sp&3)) and (bh, 2*(sp&3)+1). Register-staged
// double buffer, 1-chunk-ahead prefetch, one barrier per chunk.
template <typename T>
__global__ __launch_bounds__(256, 2) void l2_kernel_hp(
    const T* __restrict__ hsrc, const float* __restrict__ W2,
    const float* __restrict__ b2, float* __restrict__ out,
    unsigned int* __restrict__ cnt, unsigned int* __restrict__ list,
    uint32_t kp0, uint32_t kp1) {
  const int octile = blockIdx.x;  // 24
  const int b      = blockIdx.y;  // 64
  const int t = threadIdx.x;      // 256
  const int oc_local = t >> 5;    // 0..7
  const int sp = t & 31;
  const int bh = sp >> 2;         // 0..7
  const int bwp0 = 2 * (sp & 3);  // 0,2,4,6
  const int oc = octile * 8 + oc_local;

  __shared__ float hs[2][30 * 38];   // 9,120 B (stride 38: float2 + bank-safe)
  __shared__ float wsf[2][8 * 52];   // 3,328 B (w stride 52: float2-aligned)

  const T* __restrict__ hb = hsrc + (size_t)b * 86400;
  const float* __restrict__ wg = W2 + (size_t)octile * 8 * 4704;

  // staging slots (coverage: 4*256=1024>=900, 2*256=512>=392 -- AUDITED)
  int hj[4], hladdr[4]; bool hv[4];
#pragma unroll
  for (int p = 0; p < 4; ++p) {
    int j = p * 256 + t;
    hv[p] = j < 900; hj[p] = hv[p] ? j : 0;
    int r = hj[p] / 30, cc = hj[p] - r * 30;
    hladdr[p] = r * 38 + cc;
  }
  int wj[2], wladdr[2]; size_t wgoff[2]; bool wv[2];
#pragma unroll
  for (int p = 0; p < 2; ++p) {
    int j = p * 256 + t;
    wv[p] = j < 392; wj[p] = wv[p] ? j : 0;
    int oi = wj[p] / 49, rem = wj[p] - oi * 49;
    wgoff[p] = (size_t)oi * 4704 + rem;
    wladdr[p] = oi * 52 + rem;
  }

  float hr[4], wr[2];
#pragma unroll
  for (int p = 0; p < 4; ++p) if (hv[p]) hr[p] = (float)hb[hj[p]];
#pragma unroll
  for (int p = 0; p < 2; ++p) if (wv[p]) wr[p] = wg[wgoff[p]];
#pragma unroll
  for (int p = 0; p < 4; ++p) if (hv[p]) hs[0][hladdr[p]] = hr[p];
#pragma unroll
  for (int p = 0; p < 2; ++p) if (wv[p]) wsf[0][wladdr[p]] = wr[p];
#pragma unroll
  for (int p = 0; p < 4; ++p) if (hv[p]) hr[p] = (float)hb[900 + hj[p]];
#pragma unroll
  for (int p = 0; p < 2; ++p) if (wv[p]) wr[p] = wg[wgoff[p] + 49];

  double a0[9] = {}, a1[9] = {};
  float w[49];
  const float* xbase0 = &hs[0][(3 * bh) * 38 + 3 * bwp0];  // 114bh+6(sp&3): even
  const float* xbase1 = &hs[1][(3 * bh) * 38 + 3 * bwp0];

#pragma unroll 1
  for (int c = 0; c < 96; ++c) {
    __syncthreads();   // buf c&1 complete; readers of buf (c+1)&1 done
    if (c + 1 < 96) {
      const int nb = (c + 1) & 1;
#pragma unroll
      for (int p = 0; p < 4; ++p) if (hv[p]) hs[nb][hladdr[p]] = hr[p];
#pragma unroll
      for (int p = 0; p < 2; ++p) if (wv[p]) wsf[nb][wladdr[p]] = wr[p];
      if (c + 2 < 96) {
#pragma unroll
        for (int p = 0; p < 4; ++p)
          if (hv[p]) hr[p] = (float)hb[(size_t)(c + 2) * 900 + hj[p]];
#pragma unroll
        for (int p = 0; p < 2; ++p)
          if (wv[p]) wr[p] = wg[wgoff[p] + (size_t)(c + 2) * 49];
      }
    }
    {
      const float* __restrict__ wsrc = &wsf[c & 1][oc_local * 52];  // even base
      const float2* __restrict__ wp2 = (const float2*)wsrc;
#pragma unroll
      for (int k = 0; k < 24; ++k) { float2 v2 = wp2[k]; w[2 * k] = v2.x; w[2 * k + 1] = v2.y; }
      w[48] = wsrc[48];
      const float* xb = (c & 1) ? xbase1 : xbase0;
      float c0[9] = {}, c1[9] = {};
      hp_step38<0>(xb, w, c0, c1);
      hp_step38<1>(xb, w, c0, c1);
      hp_step38<2>(xb, w, c0, c1);
      hp_step38<3>(xb, w, c0, c1);
      hp_step38<4>(xb, w, c0, c1);
      hp_step38<5>(xb, w, c0, c1);
      hp_step38<6>(xb, w, c0, c1);
      hp_step38<7>(xb, w, c0, c1);
      hp_step38<8>(xb, w, c0, c1);
#pragma unroll
      for (int k = 0; k < 9; ++k) { a0[k] += (double)c0[k]; a1[k] += (double)c1[k]; }
    }
  }

  const double bb = (double)b2[oc];
#pragma unroll
  for (int j = 0; j < 2; ++j) {
    const int bwp = bwp0 + j;
    const unsigned int oid = (unsigned int)((b * 192 + oc) * 64 + bh * 8 + bwp);
    const uint64_t base = (uint64_t)oid * 9ull;
    double gap;
    double pooled = gumbel_pool9_gap(j ? a1 : a0, bb, base, kp0, kp1, &gap);
    out[oid] = (float)pooled;
    if (gap < TAU) {
      unsigned int idx = atomicAdd(cnt, 1u);
      if (idx < REDO_CAP) list[idx] = oid;
    }
  }
}

// ---------------- Layer 2 fallback (pure f64, R8/R12-verified) -------------
__global__ __launch_bounds__(256, 3) void l2_kernel_f64(
    const double* __restrict__ h1, const float* __restrict__ W2,
    const float* __restrict__ b2, float* __restrict__ out,
    uint32_t kp0, uint32_t kp1) {
  const int octile = blockIdx.x;
  const int b      = blockIdx.y;
  const int t = threadIdx.x;
  const int wave = t >> 6;
  const int oc_local = t >> 5;
  const int li = t & 31;
  const int bw = li & 7;
  const int ph = 2 * ((li >> 3) & 1) + (li >> 4);
  const int bh0 = 2 * ph;
  const int oc = octile * 8 + oc_local;

  __shared__ double hs[2][900];
  __shared__ double wsd[2][392];

  const double* __restrict__ hb = h1 + (size_t)b * 86400;
  const float* __restrict__ wg = W2 + (size_t)octile * 8 * 4704;

  double a0[9] = {}, a1[9] = {};
  double w[49];

  auto stage = [&](int c, int buf) {
    const char* gsrc = (const char*)(hb + (size_t)c * 900);
#pragma unroll
    for (int p = 0; p < 2; ++p) {
      int elt = p * 256 + t;
      if (elt < 450) {
        __builtin_amdgcn_global_load_lds(
            (const __attribute__((address_space(1))) void*)(gsrc + (size_t)elt * 16),
            (__attribute__((address_space(3))) void*)((char*)&hs[buf][0] +
                                                      (size_t)(p * 256 + wave * 64) * 16),
            16, 0, 0);
      }
    }
#pragma unroll
    for (int p = 0; p < 2; ++p) {   // TWO passes (392 > 256)
      int j = p * 256 + t;
      if (j < 392) {
        int oi = j / 49, rem = j - oi * 49;
        wsd[buf][j] = (double)wg[(size_t)oi * 4704 + c * 49 + rem];
      }
    }
  };

  stage(0, 0);
#pragma unroll 1
  for (int c = 0; c < 96; ++c) {
    __syncthreads();
    if (c + 1 < 96) stage(c + 1, (c + 1) & 1);
    {
      const double* __restrict__ wsrc = &wsd[c & 1][oc_local * 49];
#pragma unroll
      for (int j = 0; j < 49; ++j) w[j] = wsrc[j];
      const double* xb = &hs[c & 1][(6 * ph) * 30 + 3 * bw];
      conv_pair<30, double>(xb, w, a0, a1);
    }
  }

  const double bb = (double)b2[oc];
#pragma unroll
  for (int j = 0; j < 2; ++j) {
    const int bh = bh0 + j;
    const uint64_t base = ((uint64_t)(((b * 192 + oc) * 8 + bh) * 8 + bw)) * 9ull;
    double pooled = gumbel_pool9(j ? a1 : a0, bb, base, kp0, kp1);
    out[(size_t)(b * 192 + oc) * 64 + bh * 8 + bw] = (float)pooled;
  }
}

// ---------------- Layer 2 tie-redo (exact f64 from h1_f64) ----------------
__global__ __launch_bounds__(64) void l2_redo_kernel(
    const double* __restrict__ h1, const float* __restrict__ W2,
    const float* __restrict__ b2, float* __restrict__ out,
    const unsigned int* __restrict__ cnt, const unsigned int* __restrict__ list,
    uint32_t kp0, uint32_t kp1) {
  unsigned int n = *cnt;
  if (n > REDO_CAP) n = REDO_CAP;
  if (blockIdx.x >= n) return;
  const unsigned int oid = list[blockIdx.x];
  const int sp = oid & 63, bh = sp >> 3, bw = sp & 7;
  const int rest = oid >> 6, oc = rest % 192, b = rest / 192;
  const int lane = threadIdx.x;

  double acc[9] = {};
  for (int ic = lane; ic < 96; ic += 64) {
    const double* __restrict__ xp =
        h1 + ((size_t)(b * 96 + ic) * 30 + 3 * bh) * 30 + 3 * bw;
    const float* __restrict__ wp = W2 + ((size_t)oc * 96 + ic) * 49;
    double w[49];
#pragma unroll
    for (int j = 0; j < 49; ++j) w[j] = (double)wp[j];
#pragma unroll
    for (int pr = 0; pr < 9; ++pr) {
      double xr[9];
#pragma unroll
      for (int c = 0; c < 9; ++c) xr[c] = xp[pr * 30 + c];
#pragma unroll
      for (int kh = 0; kh < 3; ++kh) {
        const int u = pr - kh;
        if (u >= 0 && u <= 6) {
#pragma unroll
          for (int kw = 0; kw < 3; ++kw)
#pragma unroll
            for (int v = 0; v < 7; ++v)
              acc[kh * 3 + kw] = fma(xr[kw + v], w[u * 7 + v], acc[kh * 3 + kw]);
        }
      }
    }
  }
#pragma unroll
  for (int off = 32; off; off >>= 1)
#pragma unroll
    for (int k = 0; k < 9; ++k) acc[k] += __shfl_down(acc[k], off);

  if (lane == 0) {
    const uint64_t base = (uint64_t)oid * 9ull;
    double pooled = gumbel_pool9(acc, (double)b2[oc], base, kp0, kp1);
    out[oid] = (float)pooled;
  }
}

extern "C" void kernel_launch(void* const* d_in, const int* in_sizes, int n_in,
                              void* d_out, int out_size, void* d_ws,
                              size_t ws_size, hipStream_t stream) {
  const float* x  = (const float*)d_in[0];   // [64,3,96,96]
  const float* W1 = (const float*)d_in[1];   // [96,3,7,7]
  const float* b1 = (const float*)d_in[2];   // [96]
  const float* W2 = (const float*)d_in[3];   // [192,96,7,7]
  const float* b2 = (const float*)d_in[4];   // [192]
  float* out = (float*)d_out;                // [64,192,8,8]
  double* h1   = (double*)d_ws;              // 44.24 MB f64
  float* h1f32 = (float*)((char*)d_ws + H1_BYTES);  // 22.12 MB f32 (full tier)

  uint32_t kp1a, kp1b, kp2a, kp2b;
  threefry2x32(0u, 42u, 0u, 0u, &kp1a, &kp1b);
  threefry2x32(0u, 42u, 0u, 1u, &kp2a, &kp2b);

  const size_t need_full = H1_BYTES + H1F32_BYTES + 16 + (size_t)REDO_CAP * 4;
  const size_t need_mid  = H1_BYTES + 16 + (size_t)REDO_CAP * 4;

  if (ws_size >= need_full) {          // launch-constant branches: graph-safe
    unsigned int* cnt  = (unsigned int*)((char*)d_ws + H1_BYTES + H1F32_BYTES);
    unsigned int* list = cnt + 4;
    l1_kernel<<<dim3(96, 64, 2), 256, 0, stream>>>(x, W1, b1, h1, h1f32, 1,
                                                   cnt, kp1a, kp1b);
    l2_kernel_hp<float><<<dim3(24, 64), 256, 0, stream>>>(
        h1f32, W2, b2, out, cnt, list, kp2a, kp2b);
    l2_redo_kernel<<<REDO_CAP, 64, 0, stream>>>(h1, W2, b2, out, cnt, list,
                                                kp2a, kp2b);
  } else if (ws_size >= need_mid) {
    unsigned int* cnt  = (unsigned int*)((char*)d_ws + H1_BYTES);
    unsigned int* list = cnt + 4;
    l1_kernel<<<dim3(96, 64, 2), 256, 0, stream>>>(x, W1, b1, h1, h1f32, 0,
                                                   cnt, kp1a, kp1b);
    l2_kernel_hp<double><<<dim3(24, 64), 256, 0, stream>>>(
        h1, W2, b2, out, cnt, list, kp2a, kp2b);
    l2_redo_kernel<<<REDO_CAP, 64, 0, stream>>>(h1, W2, b2, out, cnt, list,
                                                kp2a, kp2b);
  } else {
    l1_kernel<<<dim3(96, 64, 2), 256, 0, stream>>>(x, W1, b1, h1, h1f32, 0,
                                                   (unsigned int*)0, kp1a, kp1b);
    l2_kernel_f64<<<dim3(24, 64), 256, 0, stream>>>(h1, W2, b2, out,
                                                    kp2a, kp2b);
  }
}